// Round 9
// baseline (85.665 us; speedup 1.0000x reference)
//
#include <hip/hip_runtime.h>
#include <stdint.h>

// B=8, Q=2048, D=256, H=8, L=3, P=4, HD=32
// vproj rows: level-major, T={2048,1024,512}, LOFF={0,16384,24576}, total 28672

typedef __attribute__((ext_vector_type(8))) short bf16x8;
typedef __attribute__((ext_vector_type(8))) unsigned short u16x8;
typedef __attribute__((ext_vector_type(4))) float f32x4;

__device__ __forceinline__ unsigned short f2bf(float f) {
    union { float f; uint32_t u; } v; v.f = f;
    return (unsigned short)((v.u + 0x7FFFu + ((v.u >> 16) & 1u)) >> 16);  // RNE
}
__device__ __forceinline__ float bf2f(unsigned short u) {
    union { uint32_t u; float f; } v; v.u = ((uint32_t)u) << 16;
    return v.f;
}

// ---------------------------------------------------------------------------
// K0: pre-swizzle all weights to bf16 in the GEMM staging layout
// [k0t][slot][col][kk]  (k = k0t*32 + slot*8 + kk), so B-staging = memcpy.
// ---------------------------------------------------------------------------
__global__ __launch_bounds__(256) void swizzle_w_kernel(
    const float* __restrict__ Woff, const float* __restrict__ Waw,
    const float* __restrict__ boff, const float* __restrict__ baw,
    const float* __restrict__ Wv, const float* __restrict__ Wo,
    unsigned short* __restrict__ wcat, unsigned short* __restrict__ wvs,
    unsigned short* __restrict__ wos, float* __restrict__ bcat)
{
    const int id = blockIdx.x * 256 + threadIdx.x;   // 0..147455
    float v; unsigned short* dst;
    if (id < 49152) {
        const int rel = id;
        const int kk = rel & 7, c2 = rel >> 3;
        const int col = c2 % 192, sb = c2 / 192;
        const int k = (sb >> 2) * 32 + (sb & 3) * 8 + kk;
        v = (col < 96) ? Woff[k * 96 + col] : Waw[k * 96 + (col - 96)];
        dst = wcat + rel;
    } else if (id < 81920) {
        const int rel = id - 49152;
        const int kk = rel & 7, c2 = rel >> 3;
        const int col = c2 & 127, sb = c2 >> 7;
        const int k = (sb >> 2) * 32 + (sb & 3) * 8 + kk;
        v = Wv[k * 256 + col];
        dst = wvs + rel;
    } else {
        const int rel = id - 81920;
        const int kk = rel & 7, c2 = rel >> 3;
        const int col = c2 & 255, sb = c2 >> 8;
        const int k = (sb >> 2) * 32 + (sb & 3) * 8 + kk;
        v = Wo[k * 256 + col];
        dst = wos + rel;
    }
    *dst = f2bf(v);
    if (id < 192) bcat[id] = (id < 96) ? boff[id] : baw[id - 96];
}

// ---------------------------------------------------------------------------
// K12: merged GEMMs, XCD-batch-aligned, LDS phase-union (25 KB -> 6 blocks/CU).
//  blocks 0..223  : value projection tile (batch = bid&7).
//  blocks 224..479: logits tile (batch = lid&7) + softmax + sidx, epilogue
//                   processed in two 32-row halves to fit the union buffer.
// ---------------------------------------------------------------------------
__global__ __launch_bounds__(256, 6) void fused_k12_kernel(
    const float* __restrict__ v0, const float* __restrict__ v1,
    const float* __restrict__ v2,
    const unsigned short* __restrict__ wvs, const float* __restrict__ bv,
    unsigned short* __restrict__ vproj,
    const float* __restrict__ query,
    const unsigned short* __restrict__ wcat, const float* __restrict__ bcat,
    const float* __restrict__ refp, float* __restrict__ rows)
{
    __shared__ __align__(16) char SMEM[25344];   // union: staging | epilogue
    const int t = threadIdx.x;
    const int bid = blockIdx.x;
    const int w = t >> 6, lane = t & 63;
    const int fr = lane & 15, sl = lane >> 4;

    if (bid < 224) {
        // ================= vproj path (batch = bid&7) =====================
        auto Asub = reinterpret_cast<unsigned short(*)[128][8]>(SMEM);          // 8 KB
        auto Bsub = reinterpret_cast<unsigned short(*)[128][8]>(SMEM + 8192);   // 8 KB

        const int b = bid & 7;
        const int j = bid >> 3;                  // 0..27
        int l, tile;
        if (j < 16)      { l = 0; tile = j; }
        else if (j < 24) { l = 1; tile = j - 16; }
        else             { l = 2; tile = j - 24; }
        const int T = 2048 >> l;
        const int loff = (l == 0) ? 0 : ((l == 1) ? 16384 : 24576);
        const int row0 = loff + b * T + tile * 128;
        const int arow = b * T + tile * 128;
        const float* Ap = (l == 0) ? v0 : ((l == 1) ? v1 : v2);

        const int ar = t >> 1, ah = t & 1;
        const int wr = w >> 1, wc = w & 1;

        f32x4 acc[4][4];
#pragma unroll
        for (int m = 0; m < 4; ++m)
#pragma unroll
            for (int n = 0; n < 4; ++n) acc[m][n] = (f32x4){0.f, 0.f, 0.f, 0.f};

        for (int k0t = 0; k0t < 8; ++k0t) {
            const int k0 = k0t * 32;
#pragma unroll
            for (int q = 0; q < 2; ++q) {           // stage A (f32 -> bf16)
                const int slot = ah * 2 + q;
                const float* src = &Ap[(size_t)(arow + ar) * 256 + k0 + slot * 8];
                const float4 f0 = *reinterpret_cast<const float4*>(src);
                const float4 f1 = *reinterpret_cast<const float4*>(src + 4);
                u16x8 pk;
                pk[0]=f2bf(f0.x); pk[1]=f2bf(f0.y); pk[2]=f2bf(f0.z); pk[3]=f2bf(f0.w);
                pk[4]=f2bf(f1.x); pk[5]=f2bf(f1.y); pk[6]=f2bf(f1.z); pk[7]=f2bf(f1.w);
                *reinterpret_cast<u16x8*>(&Asub[slot][ar][0]) = pk;
            }
            {                                        // stage B: pure 16B copies
                const u16x8* src = reinterpret_cast<const u16x8*>(wvs + (size_t)k0t * 4096);
#pragma unroll
                for (int i = 0; i < 2; ++i) {
                    const int ch = t + i * 256;      // 0..511
                    *reinterpret_cast<u16x8*>(&Bsub[ch >> 7][ch & 127][0]) = src[ch];
                }
            }
            __syncthreads();

            bf16x8 bfrag[4];
#pragma unroll
            for (int n = 0; n < 4; ++n)
                bfrag[n] = *reinterpret_cast<bf16x8*>(&Bsub[sl][wc * 64 + n * 16 + fr][0]);
#pragma unroll
            for (int m = 0; m < 4; ++m) {
                bf16x8 afrag = *reinterpret_cast<bf16x8*>(&Asub[sl][wr * 64 + m * 16 + fr][0]);
#pragma unroll
                for (int n = 0; n < 4; ++n)
                    acc[m][n] = __builtin_amdgcn_mfma_f32_16x16x32_bf16(afrag, bfrag[n], acc[m][n], 0, 0, 0);
            }
            __syncthreads();
        }

        float bs[4];
#pragma unroll
        for (int n = 0; n < 4; ++n) bs[n] = bv[wc * 64 + n * 16 + fr];

        auto Epi2 = reinterpret_cast<float(*)[132]>(SMEM);   // [32][132], aliases staging
#pragma unroll
        for (int m = 0; m < 4; ++m) {
#pragma unroll
            for (int n = 0; n < 4; ++n)
#pragma unroll
                for (int jj = 0; jj < 4; ++jj)
                    Epi2[wr * 16 + sl * 4 + jj][wc * 64 + n * 16 + fr] = acc[m][n][jj] + bs[n];
            __syncthreads();
#pragma unroll
            for (int i = 0; i < 2; ++i) {            // 512 short8 chunks, 2/thread
                const int idx = t + i * 256;
                const int rb = idx >> 4, c8 = idx & 15;
                const int grow = row0 + m * 16 + (rb >> 4) * 64 + (rb & 15);
                u16x8 pk;
#pragma unroll
                for (int e = 0; e < 8; ++e) pk[e] = f2bf(Epi2[rb][c8 * 8 + e]);
                *reinterpret_cast<u16x8*>(&vproj[(size_t)grow * 128 + c8 * 8]) = pk;
            }
            __syncthreads();
        }
    } else {
        // ================= logits path (batch = lid&7) ====================
        auto Asub = reinterpret_cast<unsigned short(*)[64][8]>(SMEM);           // 4 KB
        auto Bsub = reinterpret_cast<unsigned short(*)[192][8]>(SMEM + 4096);   // 12 KB

        const int lid = bid - 224;               // 224 % 8 == 0 -> lid&7 == bid&7
        const int qrow0 = (lid & 7) * 2048 + (lid >> 3) * 64;
        const int wr = w >> 1, wc = w & 1;          // wave: 32 rows x 96 cols

        f32x4 acc[2][6];
#pragma unroll
        for (int m = 0; m < 2; ++m)
#pragma unroll
            for (int n = 0; n < 6; ++n) acc[m][n] = (f32x4){0.f, 0.f, 0.f, 0.f};

        const int ar = t >> 2, as = t & 3;          // A staging: row 0..63, slot 0..3

        for (int k0t = 0; k0t < 8; ++k0t) {
            const int k0 = k0t * 32;
            {   // stage A: 64 rows x 32 k, f32 -> bf16
                const float* src = &query[(size_t)(qrow0 + ar) * 256 + k0 + as * 8];
                const float4 f0 = *reinterpret_cast<const float4*>(src);
                const float4 f1 = *reinterpret_cast<const float4*>(src + 4);
                u16x8 pk;
                pk[0]=f2bf(f0.x); pk[1]=f2bf(f0.y); pk[2]=f2bf(f0.z); pk[3]=f2bf(f0.w);
                pk[4]=f2bf(f1.x); pk[5]=f2bf(f1.y); pk[6]=f2bf(f1.z); pk[7]=f2bf(f1.w);
                *reinterpret_cast<u16x8*>(&Asub[as][ar][0]) = pk;
            }
            {   // stage B: pure 16B copies from pre-swizzled wcat
                const u16x8* src = reinterpret_cast<const u16x8*>(&wcat[(size_t)k0t * 6144]);
#pragma unroll
                for (int i = 0; i < 3; ++i) {
                    const int c = t + i * 256;      // 0..767
                    *reinterpret_cast<u16x8*>(&Bsub[c / 192][c % 192][0]) = src[c];
                }
            }
            __syncthreads();

            bf16x8 bfrag[6];
#pragma unroll
            for (int n = 0; n < 6; ++n)
                bfrag[n] = *reinterpret_cast<bf16x8*>(&Bsub[sl][wc * 96 + n * 16 + fr][0]);
#pragma unroll
            for (int m = 0; m < 2; ++m) {
                bf16x8 afrag = *reinterpret_cast<bf16x8*>(&Asub[sl][wr * 32 + m * 16 + fr][0]);
#pragma unroll
                for (int n = 0; n < 6; ++n)
                    acc[m][n] = __builtin_amdgcn_mfma_f32_16x16x32_bf16(afrag, bfrag[n], acc[m][n], 0, 0, 0);
            }
            __syncthreads();
        }

        // Epilogue in two 32-row halves through the union buffer.
        auto Epi = reinterpret_cast<float(*)[196]>(SMEM);    // [32][196], aliases staging
#pragma unroll
        for (int half = 0; half < 2; ++half) {
            if (half) __syncthreads();               // protect Epi reuse across halves
            if (wr == half) {
#pragma unroll
                for (int n = 0; n < 6; ++n) {
                    const int col = wc * 96 + n * 16 + fr;
                    const float bsn = bcat[col];
#pragma unroll
                    for (int m = 0; m < 2; ++m)
#pragma unroll
                        for (int jj = 0; jj < 4; ++jj)
                            Epi[m * 16 + sl * 4 + jj][col] = acc[m][n][jj] + bsn;
                }
            }
            __syncthreads();

            // softmax + sidx: 256 (q,h) pairs, 1 per thread
            {
                const int q = t >> 3, h = t & 7;
                const float ref = refp[qrow0 + half * 32 + q];
                float* lg = &Epi[q][96 + h * 12];
                float mx = -1e30f;
#pragma unroll
                for (int jj = 0; jj < 12; ++jj) mx = fmaxf(mx, lg[jj]);
                float e[12]; float s = 0.f;
#pragma unroll
                for (int jj = 0; jj < 12; ++jj) { e[jj] = expf(lg[jj] - mx); s += e[jj]; }
                const float inv = 1.f / s;
#pragma unroll
                for (int jj = 0; jj < 12; ++jj) lg[jj] = e[jj] * inv;
                float* off = &Epi[q][h * 12];
#pragma unroll
                for (int jj = 0; jj < 12; ++jj) {
                    const int l = jj >> 2;
                    const int T = 2048 >> l;
                    float pos = ref + off[jj] / (float)T;
                    pos = fminf(fmaxf(pos, 0.f), 1.f);
                    off[jj] = pos * (float)(T - 1);
                }
            }
            __syncthreads();

            // Coalesced writeout: 32 x 192 f32 = 1536 float4, 6 per thread.
#pragma unroll
            for (int i = 0; i < 6; ++i) {
                const int idx = t + i * 256;
                const int q = idx / 48, c4 = idx % 48;
                const float4 o = *reinterpret_cast<const float4*>(&Epi[q][c4 * 4]);
                *reinterpret_cast<float4*>(
                    &rows[(size_t)(qrow0 + half * 32 + q) * 192 + c4 * 4]) = o;
            }
        }
    }
}

// ---------------------------------------------------------------------------
// K3: gather + lerp + weighted sum, 4x vectorized.
// One wave per query (8 heads x 8 channel-quads), 4 queries per block.
// ushort4 (8B) gathers; grid 4096 with bid&7 = batch -> XCD L2 affinity.
// ---------------------------------------------------------------------------
__global__ __launch_bounds__(256) void sample_kernel(
    const float* __restrict__ rows,            // [16384,192]  sidx | aw
    const unsigned short* __restrict__ vproj,  // [28672,128]  bf16, level-major
    unsigned short* __restrict__ out_mid)      // [16384,256]  bf16
{
    const int bid = blockIdx.x;                // 0..4095
    const int b = bid & 7;
    const int q0 = (b << 11) + ((bid >> 3) << 2);   // 4 queries/block
    const int t = threadIdx.x;
    const int w = t >> 6, lane = t & 63;
    const int h = lane >> 3, c4 = lane & 7;    // channel = c4*4 .. +3

    __shared__ float srow[4][192];
    {
        const float* src = rows + (size_t)q0 * 192;
#pragma unroll
        for (int i = 0; i < 3; ++i) {
            const int idx = t + i * 256;       // 0..767, coalesced
            srow[idx / 192][idx % 192] = src[idx];
        }
    }
    __syncthreads();

    float acc0 = 0.f, acc1 = 0.f, acc2 = 0.f, acc3 = 0.f;
#pragma unroll
    for (int l = 0; l < 3; ++l) {
        const int T = 2048 >> l;
        const int loff = (l == 0) ? 0 : ((l == 1) ? 16384 : 24576);
#pragma unroll
        for (int p = 0; p < 4; ++p) {
            const int j = h * 12 + l * 4 + p;
            const float wgt  = srow[w][96 + j];
            const float sidx = srow[w][j];
            int ifl = (int)sidx;
            ifl = min(max(ifl, 0), T - 2);
            const float wce = sidx - (float)ifl;
            const size_t base = ((size_t)(loff + b * T + ifl)) * 128 + p * 32 + c4 * 4;
            const ushort4 vf = *reinterpret_cast<const ushort4*>(&vproj[base]);
            const ushort4 vc = *reinterpret_cast<const ushort4*>(&vproj[base + 128]);
            const float f0 = bf2f(vf.x), f1 = bf2f(vf.y), f2 = bf2f(vf.z), f3 = bf2f(vf.w);
            const float g0 = bf2f(vc.x), g1 = bf2f(vc.y), g2 = bf2f(vc.z), g3 = bf2f(vc.w);
            acc0 += wgt * (f0 + wce * (g0 - f0));
            acc1 += wgt * (f1 + wce * (g1 - f1));
            acc2 += wgt * (f2 + wce * (g2 - f2));
            acc3 += wgt * (f3 + wce * (g3 - f3));
        }
    }
    ushort4 o;
    o.x = f2bf(acc0); o.y = f2bf(acc1); o.z = f2bf(acc2); o.w = f2bf(acc3);
    *reinterpret_cast<ushort4*>(&out_mid[(size_t)(q0 + w) * 256 + h * 32 + c4 * 4]) = o;
}

// ---------------------------------------------------------------------------
// K4: output projection, XCD-batch-aligned, LDS phase-union (16.9 KB).
// 1D grid 256: b = bid&7, row-tile = (bid>>3)&15, col-tile = bid>>7.
// ---------------------------------------------------------------------------
__global__ __launch_bounds__(256, 6) void outproj_kernel(
    const unsigned short* __restrict__ omid,   // [16384,256] bf16
    const unsigned short* __restrict__ wos,    // pre-swizzled [8][4][256][8]
    const float* __restrict__ bo,
    float* __restrict__ out)
{
    __shared__ __align__(16) char SMEM[16896];   // union: staging 16K | epi 16.9K
    auto Asub = reinterpret_cast<unsigned short(*)[128][8]>(SMEM);          // 8 KB
    auto Bsub = reinterpret_cast<unsigned short(*)[128][8]>(SMEM + 8192);   // 8 KB

    const int t = threadIdx.x;
    const int bid = blockIdx.x;
    const int b = bid & 7;
    const int row0 = b * 2048 + ((bid >> 3) & 15) * 128;
    const int col0 = (bid >> 7) * 128;

    const int ar = t >> 1, ah = t & 1;
    const int w = t >> 6, lane = t & 63;
    const int wr = w >> 1, wc = w & 1;
    const int fr = lane & 15, sl = lane >> 4;

    f32x4 acc[4][4];
#pragma unroll
    for (int m = 0; m < 4; ++m)
#pragma unroll
        for (int n = 0; n < 4; ++n) acc[m][n] = (f32x4){0.f, 0.f, 0.f, 0.f};

    for (int k0t = 0; k0t < 8; ++k0t) {
        const int k0 = k0t * 32;
#pragma unroll
        for (int q = 0; q < 2; ++q) {           // stage A: 16B copies (bf16 src)
            const int slot = ah * 2 + q;
            *reinterpret_cast<u16x8*>(&Asub[slot][ar][0]) =
                *reinterpret_cast<const u16x8*>(&omid[(size_t)(row0 + ar) * 256 + k0 + slot * 8]);
        }
        {                                        // stage B: 16B copies from wos
            const u16x8* src = reinterpret_cast<const u16x8*>(wos + (size_t)k0t * 8192);
#pragma unroll
            for (int i = 0; i < 2; ++i) {
                const int ch = t + i * 256;      // 0..511
                *reinterpret_cast<u16x8*>(&Bsub[ch >> 7][ch & 127][0]) =
                    src[(ch >> 7) * 256 + col0 + (ch & 127)];
            }
        }
        __syncthreads();

        bf16x8 bfrag[4];
#pragma unroll
        for (int n = 0; n < 4; ++n)
            bfrag[n] = *reinterpret_cast<bf16x8*>(&Bsub[sl][wc * 64 + n * 16 + fr][0]);
#pragma unroll
        for (int m = 0; m < 4; ++m) {
            bf16x8 afrag = *reinterpret_cast<bf16x8*>(&Asub[sl][wr * 64 + m * 16 + fr][0]);
#pragma unroll
            for (int n = 0; n < 4; ++n)
                acc[m][n] = __builtin_amdgcn_mfma_f32_16x16x32_bf16(afrag, bfrag[n], acc[m][n], 0, 0, 0);
        }
        __syncthreads();
    }

    float bs[4];
#pragma unroll
    for (int n = 0; n < 4; ++n) bs[n] = bo[col0 + wc * 64 + n * 16 + fr];

    auto Epi2 = reinterpret_cast<float(*)[132]>(SMEM);   // [32][132], aliases staging
#pragma unroll
    for (int m = 0; m < 4; ++m) {
#pragma unroll
        for (int n = 0; n < 4; ++n)
#pragma unroll
            for (int j = 0; j < 4; ++j)
                Epi2[wr * 16 + sl * 4 + j][wc * 64 + n * 16 + fr] = acc[m][n][j] + bs[n];
        __syncthreads();
#pragma unroll
        for (int i = 0; i < 4; ++i) {            // 1024 float4 chunks, 4/thread
            const int idx = t + i * 256;
            const int rb = idx >> 5, c4 = idx & 31;
            const int grow = row0 + m * 16 + (rb >> 4) * 64 + (rb & 15);
            const float4 o = *reinterpret_cast<const float4*>(&Epi2[rb][c4 * 4]);
            *reinterpret_cast<float4*>(&out[(size_t)grow * 256 + col0 + c4 * 4]) = o;
        }
        __syncthreads();
    }
}

extern "C" void kernel_launch(void* const* d_in, const int* in_sizes, int n_in,
                              void* d_out, int out_size, void* d_ws, size_t ws_size,
                              hipStream_t stream) {
    (void)in_sizes; (void)n_in; (void)out_size; (void)ws_size;
    const float* query = (const float*)d_in[0];
    const float* refp  = (const float*)d_in[1];
    const float* v0    = (const float*)d_in[2];
    const float* v1    = (const float*)d_in[3];
    const float* v2    = (const float*)d_in[4];
    const float* Woff  = (const float*)d_in[5];
    const float* boff  = (const float*)d_in[6];
    const float* Waw   = (const float*)d_in[7];
    const float* baw   = (const float*)d_in[8];
    const float* Wv    = (const float*)d_in[9];
    const float* bv    = (const float*)d_in[10];
    const float* Wo    = (const float*)d_in[11];
    const float* bo    = (const float*)d_in[12];
    float* out = (float*)d_out;

    char* ws = (char*)d_ws;
    unsigned short* vproj = (unsigned short*)(ws);             // 7,340,032 B
    float*          rows  = (float*)(ws + 7340032);            // 12,582,912 B
    unsigned short* omid  = (unsigned short*)(ws + 19922944);  // 8,388,608 B
    unsigned short* wcat  = (unsigned short*)(ws + 28311552);  //    98,304 B
    unsigned short* wvs   = (unsigned short*)(ws + 28409856);  //    65,536 B
    unsigned short* wos   = (unsigned short*)(ws + 28475392);  //   131,072 B
    float*          bcat  = (float*)(ws + 28606464);           //       768 B

    // K0: weight pre-swizzle (bf16, staging layout)
    swizzle_w_kernel<<<576, 256, 0, stream>>>(Woff, Waw, boff, baw, Wv, Wo,
                                              wcat, wvs, wos, bcat);

    // K12: merged vproj + logits/softmax/sidx, XCD-aligned, high occupancy
    fused_k12_kernel<<<480, 256, 0, stream>>>(v0, v1, v2, wvs, bv, vproj,
                                              query, wcat, bcat, refp, rows);

    // K3: gather + lerp + weighted sum (vectorized, XCD-aligned)
    sample_kernel<<<4096, 256, 0, stream>>>(rows, vproj, omid);

    // K4: output projection (XCD-aligned, high occupancy)
    outproj_kernel<<<256, 256, 0, stream>>>(omid, wos, bo, out);
}

// Round 11
// 54.130 us; speedup vs baseline: 1.5826x; 1.5826x over previous
//
#include <hip/hip_runtime.h>
#include <stdint.h>

// B=8, Q=2048, D=256, H=8, L=3, P=4, HD=32
// vproj rows: level-major, T={2048,1024,512}, LOFF={0,16384,24576}, total 28672

typedef __attribute__((ext_vector_type(8))) short bf16x8;
typedef __attribute__((ext_vector_type(8))) unsigned short u16x8;
typedef __attribute__((ext_vector_type(4))) float f32x4;

__device__ __forceinline__ unsigned short f2bf(float f) {
    union { float f; uint32_t u; } v; v.f = f;
    return (unsigned short)((v.u + 0x7FFFu + ((v.u >> 16) & 1u)) >> 16);  // RNE
}
__device__ __forceinline__ float bf2f(unsigned short u) {
    union { uint32_t u; float f; } v; v.u = ((uint32_t)u) << 16;
    return v.f;
}

// ---------------------------------------------------------------------------
// K0: pre-swizzle all weights to bf16 in the GEMM staging layout
// [k0t][slot][col][kk]  (k = k0t*32 + slot*8 + kk), so B-staging = memcpy.
// ---------------------------------------------------------------------------
__global__ __launch_bounds__(256) void swizzle_w_kernel(
    const float* __restrict__ Woff, const float* __restrict__ Waw,
    const float* __restrict__ boff, const float* __restrict__ baw,
    const float* __restrict__ Wv, const float* __restrict__ Wo,
    unsigned short* __restrict__ wcat, unsigned short* __restrict__ wvs,
    unsigned short* __restrict__ wos, float* __restrict__ bcat)
{
    const int id = blockIdx.x * 256 + threadIdx.x;   // 0..147455
    float v; unsigned short* dst;
    if (id < 49152) {
        const int rel = id;
        const int kk = rel & 7, c2 = rel >> 3;
        const int col = c2 % 192, sb = c2 / 192;
        const int k = (sb >> 2) * 32 + (sb & 3) * 8 + kk;
        v = (col < 96) ? Woff[k * 96 + col] : Waw[k * 96 + (col - 96)];
        dst = wcat + rel;
    } else if (id < 81920) {
        const int rel = id - 49152;
        const int kk = rel & 7, c2 = rel >> 3;
        const int col = c2 & 127, sb = c2 >> 7;
        const int k = (sb >> 2) * 32 + (sb & 3) * 8 + kk;
        v = Wv[k * 256 + col];
        dst = wvs + rel;
    } else {
        const int rel = id - 81920;
        const int kk = rel & 7, c2 = rel >> 3;
        const int col = c2 & 255, sb = c2 >> 8;
        const int k = (sb >> 2) * 32 + (sb & 3) * 8 + kk;
        v = Wo[k * 256 + col];
        dst = wos + rel;
    }
    *dst = f2bf(v);
    if (id < 192) bcat[id] = (id < 96) ? boff[id] : baw[id - 96];
}

// ---------------------------------------------------------------------------
// K12: merged GEMMs, XCD-batch-aligned, LDS phase-union (25 KB).
// NOTE: no min-waves launch_bounds arg — round 9 showed (256,6) caps VGPR at
// 40 and spills the 64-VGPR accumulators to scratch (70 MB HBM spill traffic).
// At natural ~84 VGPR + 25.3 KB LDS the occupancy is 6 blocks/CU anyway.
//  blocks 0..223  : value projection tile (batch = bid&7).
//  blocks 224..479: logits tile (batch = lid&7) + softmax + sidx, epilogue
//                   processed in two 32-row halves to fit the union buffer.
// ---------------------------------------------------------------------------
__global__ __launch_bounds__(256) void fused_k12_kernel(
    const float* __restrict__ v0, const float* __restrict__ v1,
    const float* __restrict__ v2,
    const unsigned short* __restrict__ wvs, const float* __restrict__ bv,
    unsigned short* __restrict__ vproj,
    const float* __restrict__ query,
    const unsigned short* __restrict__ wcat, const float* __restrict__ bcat,
    const float* __restrict__ refp, float* __restrict__ rows)
{
    __shared__ __align__(16) char SMEM[25344];   // union: staging | epilogue
    const int t = threadIdx.x;
    const int bid = blockIdx.x;
    const int w = t >> 6, lane = t & 63;
    const int fr = lane & 15, sl = lane >> 4;

    if (bid < 224) {
        // ================= vproj path (batch = bid&7) =====================
        auto Asub = reinterpret_cast<unsigned short(*)[128][8]>(SMEM);          // 8 KB
        auto Bsub = reinterpret_cast<unsigned short(*)[128][8]>(SMEM + 8192);   // 8 KB

        const int b = bid & 7;
        const int j = bid >> 3;                  // 0..27
        int l, tile;
        if (j < 16)      { l = 0; tile = j; }
        else if (j < 24) { l = 1; tile = j - 16; }
        else             { l = 2; tile = j - 24; }
        const int T = 2048 >> l;
        const int loff = (l == 0) ? 0 : ((l == 1) ? 16384 : 24576);
        const int row0 = loff + b * T + tile * 128;
        const int arow = b * T + tile * 128;
        const float* Ap = (l == 0) ? v0 : ((l == 1) ? v1 : v2);

        const int ar = t >> 1, ah = t & 1;
        const int wr = w >> 1, wc = w & 1;

        f32x4 acc[4][4];
#pragma unroll
        for (int m = 0; m < 4; ++m)
#pragma unroll
            for (int n = 0; n < 4; ++n) acc[m][n] = (f32x4){0.f, 0.f, 0.f, 0.f};

        for (int k0t = 0; k0t < 8; ++k0t) {
            const int k0 = k0t * 32;
#pragma unroll
            for (int q = 0; q < 2; ++q) {           // stage A (f32 -> bf16)
                const int slot = ah * 2 + q;
                const float* src = &Ap[(size_t)(arow + ar) * 256 + k0 + slot * 8];
                const float4 f0 = *reinterpret_cast<const float4*>(src);
                const float4 f1 = *reinterpret_cast<const float4*>(src + 4);
                u16x8 pk;
                pk[0]=f2bf(f0.x); pk[1]=f2bf(f0.y); pk[2]=f2bf(f0.z); pk[3]=f2bf(f0.w);
                pk[4]=f2bf(f1.x); pk[5]=f2bf(f1.y); pk[6]=f2bf(f1.z); pk[7]=f2bf(f1.w);
                *reinterpret_cast<u16x8*>(&Asub[slot][ar][0]) = pk;
            }
            {                                        // stage B: pure 16B copies
                const u16x8* src = reinterpret_cast<const u16x8*>(wvs + (size_t)k0t * 4096);
#pragma unroll
                for (int i = 0; i < 2; ++i) {
                    const int ch = t + i * 256;      // 0..511
                    *reinterpret_cast<u16x8*>(&Bsub[ch >> 7][ch & 127][0]) = src[ch];
                }
            }
            __syncthreads();

            bf16x8 bfrag[4];
#pragma unroll
            for (int n = 0; n < 4; ++n)
                bfrag[n] = *reinterpret_cast<bf16x8*>(&Bsub[sl][wc * 64 + n * 16 + fr][0]);
#pragma unroll
            for (int m = 0; m < 4; ++m) {
                bf16x8 afrag = *reinterpret_cast<bf16x8*>(&Asub[sl][wr * 64 + m * 16 + fr][0]);
#pragma unroll
                for (int n = 0; n < 4; ++n)
                    acc[m][n] = __builtin_amdgcn_mfma_f32_16x16x32_bf16(afrag, bfrag[n], acc[m][n], 0, 0, 0);
            }
            __syncthreads();
        }

        float bs[4];
#pragma unroll
        for (int n = 0; n < 4; ++n) bs[n] = bv[wc * 64 + n * 16 + fr];

        auto Epi2 = reinterpret_cast<float(*)[132]>(SMEM);   // [32][132], aliases staging
#pragma unroll
        for (int m = 0; m < 4; ++m) {
#pragma unroll
            for (int n = 0; n < 4; ++n)
#pragma unroll
                for (int jj = 0; jj < 4; ++jj)
                    Epi2[wr * 16 + sl * 4 + jj][wc * 64 + n * 16 + fr] = acc[m][n][jj] + bs[n];
            __syncthreads();
#pragma unroll
            for (int i = 0; i < 2; ++i) {            // 512 short8 chunks, 2/thread
                const int idx = t + i * 256;
                const int rb = idx >> 4, c8 = idx & 15;
                const int grow = row0 + m * 16 + (rb >> 4) * 64 + (rb & 15);
                u16x8 pk;
#pragma unroll
                for (int e = 0; e < 8; ++e) pk[e] = f2bf(Epi2[rb][c8 * 8 + e]);
                *reinterpret_cast<u16x8*>(&vproj[(size_t)grow * 128 + c8 * 8]) = pk;
            }
            __syncthreads();
        }
    } else {
        // ================= logits path (batch = lid&7) ====================
        auto Asub = reinterpret_cast<unsigned short(*)[64][8]>(SMEM);           // 4 KB
        auto Bsub = reinterpret_cast<unsigned short(*)[192][8]>(SMEM + 4096);   // 12 KB

        const int lid = bid - 224;               // 224 % 8 == 0 -> lid&7 == bid&7
        const int qrow0 = (lid & 7) * 2048 + (lid >> 3) * 64;
        const int wr = w >> 1, wc = w & 1;          // wave: 32 rows x 96 cols

        f32x4 acc[2][6];
#pragma unroll
        for (int m = 0; m < 2; ++m)
#pragma unroll
            for (int n = 0; n < 6; ++n) acc[m][n] = (f32x4){0.f, 0.f, 0.f, 0.f};

        const int ar = t >> 2, as = t & 3;          // A staging: row 0..63, slot 0..3

        for (int k0t = 0; k0t < 8; ++k0t) {
            const int k0 = k0t * 32;
            {   // stage A: 64 rows x 32 k, f32 -> bf16
                const float* src = &query[(size_t)(qrow0 + ar) * 256 + k0 + as * 8];
                const float4 f0 = *reinterpret_cast<const float4*>(src);
                const float4 f1 = *reinterpret_cast<const float4*>(src + 4);
                u16x8 pk;
                pk[0]=f2bf(f0.x); pk[1]=f2bf(f0.y); pk[2]=f2bf(f0.z); pk[3]=f2bf(f0.w);
                pk[4]=f2bf(f1.x); pk[5]=f2bf(f1.y); pk[6]=f2bf(f1.z); pk[7]=f2bf(f1.w);
                *reinterpret_cast<u16x8*>(&Asub[as][ar][0]) = pk;
            }
            {   // stage B: pure 16B copies from pre-swizzled wcat
                const u16x8* src = reinterpret_cast<const u16x8*>(&wcat[(size_t)k0t * 6144]);
#pragma unroll
                for (int i = 0; i < 3; ++i) {
                    const int c = t + i * 256;      // 0..767
                    *reinterpret_cast<u16x8*>(&Bsub[c / 192][c % 192][0]) = src[c];
                }
            }
            __syncthreads();

            bf16x8 bfrag[6];
#pragma unroll
            for (int n = 0; n < 6; ++n)
                bfrag[n] = *reinterpret_cast<bf16x8*>(&Bsub[sl][wc * 96 + n * 16 + fr][0]);
#pragma unroll
            for (int m = 0; m < 2; ++m) {
                bf16x8 afrag = *reinterpret_cast<bf16x8*>(&Asub[sl][wr * 32 + m * 16 + fr][0]);
#pragma unroll
                for (int n = 0; n < 6; ++n)
                    acc[m][n] = __builtin_amdgcn_mfma_f32_16x16x32_bf16(afrag, bfrag[n], acc[m][n], 0, 0, 0);
            }
            __syncthreads();
        }

        // Epilogue in two 32-row halves through the union buffer.
        auto Epi = reinterpret_cast<float(*)[196]>(SMEM);    // [32][196], aliases staging
#pragma unroll
        for (int half = 0; half < 2; ++half) {
            if (half) __syncthreads();               // protect Epi reuse across halves
            if (wr == half) {
#pragma unroll
                for (int n = 0; n < 6; ++n) {
                    const int col = wc * 96 + n * 16 + fr;
                    const float bsn = bcat[col];
#pragma unroll
                    for (int m = 0; m < 2; ++m)
#pragma unroll
                        for (int jj = 0; jj < 4; ++jj)
                            Epi[m * 16 + sl * 4 + jj][col] = acc[m][n][jj] + bsn;
                }
            }
            __syncthreads();

            // softmax + sidx: 256 (q,h) pairs, 1 per thread
            {
                const int q = t >> 3, h = t & 7;
                const float ref = refp[qrow0 + half * 32 + q];
                float* lg = &Epi[q][96 + h * 12];
                float mx = -1e30f;
#pragma unroll
                for (int jj = 0; jj < 12; ++jj) mx = fmaxf(mx, lg[jj]);
                float e[12]; float s = 0.f;
#pragma unroll
                for (int jj = 0; jj < 12; ++jj) { e[jj] = expf(lg[jj] - mx); s += e[jj]; }
                const float inv = 1.f / s;
#pragma unroll
                for (int jj = 0; jj < 12; ++jj) lg[jj] = e[jj] * inv;
                float* off = &Epi[q][h * 12];
#pragma unroll
                for (int jj = 0; jj < 12; ++jj) {
                    const int l = jj >> 2;
                    const int T = 2048 >> l;
                    float pos = ref + off[jj] / (float)T;
                    pos = fminf(fmaxf(pos, 0.f), 1.f);
                    off[jj] = pos * (float)(T - 1);
                }
            }
            __syncthreads();

            // Coalesced writeout: 32 x 192 f32 = 1536 float4, 6 per thread.
#pragma unroll
            for (int i = 0; i < 6; ++i) {
                const int idx = t + i * 256;
                const int q = idx / 48, c4 = idx % 48;
                const float4 o = *reinterpret_cast<const float4*>(&Epi[q][c4 * 4]);
                *reinterpret_cast<float4*>(
                    &rows[(size_t)(qrow0 + half * 32 + q) * 192 + c4 * 4]) = o;
            }
        }
    }
}

// ---------------------------------------------------------------------------
// K3: gather + lerp + weighted sum, 4x vectorized.
// One wave per query (8 heads x 8 channel-quads), 4 queries per block.
// ushort4 (8B) gathers; grid 4096 with bid&7 = batch -> XCD L2 affinity.
// ---------------------------------------------------------------------------
__global__ __launch_bounds__(256) void sample_kernel(
    const float* __restrict__ rows,            // [16384,192]  sidx | aw
    const unsigned short* __restrict__ vproj,  // [28672,128]  bf16, level-major
    unsigned short* __restrict__ out_mid)      // [16384,256]  bf16
{
    const int bid = blockIdx.x;                // 0..4095
    const int b = bid & 7;
    const int q0 = (b << 11) + ((bid >> 3) << 2);   // 4 queries/block
    const int t = threadIdx.x;
    const int w = t >> 6, lane = t & 63;
    const int h = lane >> 3, c4 = lane & 7;    // channel = c4*4 .. +3

    __shared__ float srow[4][192];
    {
        const float* src = rows + (size_t)q0 * 192;
#pragma unroll
        for (int i = 0; i < 3; ++i) {
            const int idx = t + i * 256;       // 0..767, coalesced
            srow[idx / 192][idx % 192] = src[idx];
        }
    }
    __syncthreads();

    float acc0 = 0.f, acc1 = 0.f, acc2 = 0.f, acc3 = 0.f;
#pragma unroll
    for (int l = 0; l < 3; ++l) {
        const int T = 2048 >> l;
        const int loff = (l == 0) ? 0 : ((l == 1) ? 16384 : 24576);
#pragma unroll
        for (int p = 0; p < 4; ++p) {
            const int j = h * 12 + l * 4 + p;
            const float wgt  = srow[w][96 + j];
            const float sidx = srow[w][j];
            int ifl = (int)sidx;
            ifl = min(max(ifl, 0), T - 2);
            const float wce = sidx - (float)ifl;
            const size_t base = ((size_t)(loff + b * T + ifl)) * 128 + p * 32 + c4 * 4;
            const ushort4 vf = *reinterpret_cast<const ushort4*>(&vproj[base]);
            const ushort4 vc = *reinterpret_cast<const ushort4*>(&vproj[base + 128]);
            const float f0 = bf2f(vf.x), f1 = bf2f(vf.y), f2 = bf2f(vf.z), f3 = bf2f(vf.w);
            const float g0 = bf2f(vc.x), g1 = bf2f(vc.y), g2 = bf2f(vc.z), g3 = bf2f(vc.w);
            acc0 += wgt * (f0 + wce * (g0 - f0));
            acc1 += wgt * (f1 + wce * (g1 - f1));
            acc2 += wgt * (f2 + wce * (g2 - f2));
            acc3 += wgt * (f3 + wce * (g3 - f3));
        }
    }
    ushort4 o;
    o.x = f2bf(acc0); o.y = f2bf(acc1); o.z = f2bf(acc2); o.w = f2bf(acc3);
    *reinterpret_cast<ushort4*>(&out_mid[(size_t)(q0 + w) * 256 + h * 32 + c4 * 4]) = o;
}

// ---------------------------------------------------------------------------
// K4: output projection, XCD-batch-aligned, LDS phase-union (16.9 KB).
// 1D grid 256: b = bid&7, row-tile = (bid>>3)&15, col-tile = bid>>7.
// ---------------------------------------------------------------------------
__global__ __launch_bounds__(256) void outproj_kernel(
    const unsigned short* __restrict__ omid,   // [16384,256] bf16
    const unsigned short* __restrict__ wos,    // pre-swizzled [8][4][256][8]
    const float* __restrict__ bo,
    float* __restrict__ out)
{
    __shared__ __align__(16) char SMEM[16896];   // union: staging 16K | epi 16.9K
    auto Asub = reinterpret_cast<unsigned short(*)[128][8]>(SMEM);          // 8 KB
    auto Bsub = reinterpret_cast<unsigned short(*)[128][8]>(SMEM + 8192);   // 8 KB

    const int t = threadIdx.x;
    const int bid = blockIdx.x;
    const int b = bid & 7;
    const int row0 = b * 2048 + ((bid >> 3) & 15) * 128;
    const int col0 = (bid >> 7) * 128;

    const int ar = t >> 1, ah = t & 1;
    const int w = t >> 6, lane = t & 63;
    const int wr = w >> 1, wc = w & 1;
    const int fr = lane & 15, sl = lane >> 4;

    f32x4 acc[4][4];
#pragma unroll
    for (int m = 0; m < 4; ++m)
#pragma unroll
        for (int n = 0; n < 4; ++n) acc[m][n] = (f32x4){0.f, 0.f, 0.f, 0.f};

    for (int k0t = 0; k0t < 8; ++k0t) {
        const int k0 = k0t * 32;
#pragma unroll
        for (int q = 0; q < 2; ++q) {           // stage A: 16B copies (bf16 src)
            const int slot = ah * 2 + q;
            *reinterpret_cast<u16x8*>(&Asub[slot][ar][0]) =
                *reinterpret_cast<const u16x8*>(&omid[(size_t)(row0 + ar) * 256 + k0 + slot * 8]);
        }
        {                                        // stage B: 16B copies from wos
            const u16x8* src = reinterpret_cast<const u16x8*>(wos + (size_t)k0t * 8192);
#pragma unroll
            for (int i = 0; i < 2; ++i) {
                const int ch = t + i * 256;      // 0..511
                *reinterpret_cast<u16x8*>(&Bsub[ch >> 7][ch & 127][0]) =
                    src[(ch >> 7) * 256 + col0 + (ch & 127)];
            }
        }
        __syncthreads();

        bf16x8 bfrag[4];
#pragma unroll
        for (int n = 0; n < 4; ++n)
            bfrag[n] = *reinterpret_cast<bf16x8*>(&Bsub[sl][wc * 64 + n * 16 + fr][0]);
#pragma unroll
        for (int m = 0; m < 4; ++m) {
            bf16x8 afrag = *reinterpret_cast<bf16x8*>(&Asub[sl][wr * 64 + m * 16 + fr][0]);
#pragma unroll
            for (int n = 0; n < 4; ++n)
                acc[m][n] = __builtin_amdgcn_mfma_f32_16x16x32_bf16(afrag, bfrag[n], acc[m][n], 0, 0, 0);
        }
        __syncthreads();
    }

    float bs[4];
#pragma unroll
    for (int n = 0; n < 4; ++n) bs[n] = bo[col0 + wc * 64 + n * 16 + fr];

    auto Epi2 = reinterpret_cast<float(*)[132]>(SMEM);   // [32][132], aliases staging
#pragma unroll
    for (int m = 0; m < 4; ++m) {
#pragma unroll
        for (int n = 0; n < 4; ++n)
#pragma unroll
            for (int j = 0; j < 4; ++j)
                Epi2[wr * 16 + sl * 4 + j][wc * 64 + n * 16 + fr] = acc[m][n][j] + bs[n];
        __syncthreads();
#pragma unroll
        for (int i = 0; i < 4; ++i) {            // 1024 float4 chunks, 4/thread
            const int idx = t + i * 256;
            const int rb = idx >> 5, c4 = idx & 31;
            const int grow = row0 + m * 16 + (rb >> 4) * 64 + (rb & 15);
            const float4 o = *reinterpret_cast<const float4*>(&Epi2[rb][c4 * 4]);
            *reinterpret_cast<float4*>(&out[(size_t)grow * 256 + col0 + c4 * 4]) = o;
        }
        __syncthreads();
    }
}

extern "C" void kernel_launch(void* const* d_in, const int* in_sizes, int n_in,
                              void* d_out, int out_size, void* d_ws, size_t ws_size,
                              hipStream_t stream) {
    (void)in_sizes; (void)n_in; (void)out_size; (void)ws_size;
    const float* query = (const float*)d_in[0];
    const float* refp  = (const float*)d_in[1];
    const float* v0    = (const float*)d_in[2];
    const float* v1    = (const float*)d_in[3];
    const float* v2    = (const float*)d_in[4];
    const float* Woff  = (const float*)d_in[5];
    const float* boff  = (const float*)d_in[6];
    const float* Waw   = (const float*)d_in[7];
    const float* baw   = (const float*)d_in[8];
    const float* Wv    = (const float*)d_in[9];
    const float* bv    = (const float*)d_in[10];
    const float* Wo    = (const float*)d_in[11];
    const float* bo    = (const float*)d_in[12];
    float* out = (float*)d_out;

    char* ws = (char*)d_ws;
    unsigned short* vproj = (unsigned short*)(ws);             // 7,340,032 B
    float*          rows  = (float*)(ws + 7340032);            // 12,582,912 B
    unsigned short* omid  = (unsigned short*)(ws + 19922944);  // 8,388,608 B
    unsigned short* wcat  = (unsigned short*)(ws + 28311552);  //    98,304 B
    unsigned short* wvs   = (unsigned short*)(ws + 28409856);  //    65,536 B
    unsigned short* wos   = (unsigned short*)(ws + 28475392);  //   131,072 B
    float*          bcat  = (float*)(ws + 28606464);           //       768 B

    // K0: weight pre-swizzle (bf16, staging layout)
    swizzle_w_kernel<<<576, 256, 0, stream>>>(Woff, Waw, boff, baw, Wv, Wo,
                                              wcat, wvs, wos, bcat);

    // K12: merged vproj + logits/softmax/sidx, XCD-aligned, LDS-union
    fused_k12_kernel<<<480, 256, 0, stream>>>(v0, v1, v2, wvs, bv, vproj,
                                              query, wcat, bcat, refp, rows);

    // K3: gather + lerp + weighted sum (vectorized, XCD-aligned)
    sample_kernel<<<4096, 256, 0, stream>>>(rows, vproj, omid);

    // K4: output projection (XCD-aligned, LDS-union)
    outproj_kernel<<<256, 256, 0, stream>>>(omid, wos, bo, out);
}

// Round 12
// 49.847 us; speedup vs baseline: 1.7186x; 1.0859x over previous
//
#include <hip/hip_runtime.h>
#include <stdint.h>

// B=8, Q=2048, D=256, H=8, L=3, P=4, HD=32
// vproj rows: level-major, T={2048,1024,512}, LOFF={0,16384,24576}, total 28672

typedef __attribute__((ext_vector_type(8))) short bf16x8;
typedef __attribute__((ext_vector_type(8))) unsigned short u16x8;
typedef __attribute__((ext_vector_type(4))) float f32x4;

__device__ __forceinline__ unsigned short f2bf(float f) {
    union { float f; uint32_t u; } v; v.f = f;
    return (unsigned short)((v.u + 0x7FFFu + ((v.u >> 16) & 1u)) >> 16);  // RNE
}
__device__ __forceinline__ float bf2f(unsigned short u) {
    union { uint32_t u; float f; } v; v.u = ((uint32_t)u) << 16;
    return v.f;
}

// ---------------------------------------------------------------------------
// K12: merged GEMMs, XCD-batch-aligned, LDS phase-union (25 KB).
// B-tiles staged directly from the raw f32 weights (L2-hot after first tile;
// lane-contiguous cols -> coalesced). K0 pre-swizzle kernel deleted.
//  blocks 0..223  : value projection tile (batch = bid&7).
//  blocks 224..479: logits tile (batch = lid&7) + softmax + sidx, epilogue
//                   processed in two 32-row halves to fit the union buffer.
// NOTE: no min-waves launch_bounds arg — (256,6) caps VGPR at 40 and spills
// the 64-VGPR accumulators (round 9: 70 MB HBM spill traffic).
// ---------------------------------------------------------------------------
__global__ __launch_bounds__(256) void fused_k12_kernel(
    const float* __restrict__ v0, const float* __restrict__ v1,
    const float* __restrict__ v2,
    const float* __restrict__ Wv, const float* __restrict__ bv,
    unsigned short* __restrict__ vproj,
    const float* __restrict__ query,
    const float* __restrict__ Woff, const float* __restrict__ Waw,
    const float* __restrict__ boff, const float* __restrict__ baw,
    const float* __restrict__ refp, float* __restrict__ rows)
{
    __shared__ __align__(16) char SMEM[25344];   // union: staging | epilogue
    const int t = threadIdx.x;
    const int bid = blockIdx.x;
    const int w = t >> 6, lane = t & 63;
    const int fr = lane & 15, sl = lane >> 4;

    if (bid < 224) {
        // ================= vproj path (batch = bid&7) =====================
        auto Asub = reinterpret_cast<unsigned short(*)[128][8]>(SMEM);          // 8 KB
        auto Bsub = reinterpret_cast<unsigned short(*)[128][8]>(SMEM + 8192);   // 8 KB

        const int b = bid & 7;
        const int j = bid >> 3;                  // 0..27
        int l, tile;
        if (j < 16)      { l = 0; tile = j; }
        else if (j < 24) { l = 1; tile = j - 16; }
        else             { l = 2; tile = j - 24; }
        const int T = 2048 >> l;
        const int loff = (l == 0) ? 0 : ((l == 1) ? 16384 : 24576);
        const int row0 = loff + b * T + tile * 128;
        const int arow = b * T + tile * 128;
        const float* Ap = (l == 0) ? v0 : ((l == 1) ? v1 : v2);

        const int ar = t >> 1, ah = t & 1;
        const int wr = w >> 1, wc = w & 1;

        f32x4 acc[4][4];
#pragma unroll
        for (int m = 0; m < 4; ++m)
#pragma unroll
            for (int n = 0; n < 4; ++n) acc[m][n] = (f32x4){0.f, 0.f, 0.f, 0.f};

        for (int k0t = 0; k0t < 8; ++k0t) {
            const int k0 = k0t * 32;
#pragma unroll
            for (int q = 0; q < 2; ++q) {           // stage A (f32 -> bf16)
                const int slot = ah * 2 + q;
                const float* src = &Ap[(size_t)(arow + ar) * 256 + k0 + slot * 8];
                const float4 f0 = *reinterpret_cast<const float4*>(src);
                const float4 f1 = *reinterpret_cast<const float4*>(src + 4);
                u16x8 pk;
                pk[0]=f2bf(f0.x); pk[1]=f2bf(f0.y); pk[2]=f2bf(f0.z); pk[3]=f2bf(f0.w);
                pk[4]=f2bf(f1.x); pk[5]=f2bf(f1.y); pk[6]=f2bf(f1.z); pk[7]=f2bf(f1.w);
                *reinterpret_cast<u16x8*>(&Asub[slot][ar][0]) = pk;
            }
            {                                        // stage B from raw Wv (cols 0..127)
#pragma unroll
                for (int i = 0; i < 2; ++i) {
                    const int ch = t + i * 256;      // 0..511
                    const int slot = ch >> 7, col = ch & 127;
                    u16x8 pk;
#pragma unroll
                    for (int jj = 0; jj < 8; ++jj)
                        pk[jj] = f2bf(Wv[(size_t)(k0 + slot * 8 + jj) * 256 + col]);
                    *reinterpret_cast<u16x8*>(&Bsub[slot][col][0]) = pk;
                }
            }
            __syncthreads();

            bf16x8 bfrag[4];
#pragma unroll
            for (int n = 0; n < 4; ++n)
                bfrag[n] = *reinterpret_cast<bf16x8*>(&Bsub[sl][wc * 64 + n * 16 + fr][0]);
#pragma unroll
            for (int m = 0; m < 4; ++m) {
                bf16x8 afrag = *reinterpret_cast<bf16x8*>(&Asub[sl][wr * 64 + m * 16 + fr][0]);
#pragma unroll
                for (int n = 0; n < 4; ++n)
                    acc[m][n] = __builtin_amdgcn_mfma_f32_16x16x32_bf16(afrag, bfrag[n], acc[m][n], 0, 0, 0);
            }
            __syncthreads();
        }

        float bs[4];
#pragma unroll
        for (int n = 0; n < 4; ++n) bs[n] = bv[wc * 64 + n * 16 + fr];

        auto Epi2 = reinterpret_cast<float(*)[132]>(SMEM);   // [32][132], aliases staging
#pragma unroll
        for (int m = 0; m < 4; ++m) {
#pragma unroll
            for (int n = 0; n < 4; ++n)
#pragma unroll
                for (int jj = 0; jj < 4; ++jj)
                    Epi2[wr * 16 + sl * 4 + jj][wc * 64 + n * 16 + fr] = acc[m][n][jj] + bs[n];
            __syncthreads();
#pragma unroll
            for (int i = 0; i < 2; ++i) {            // 512 short8 chunks, 2/thread
                const int idx = t + i * 256;
                const int rb = idx >> 4, c8 = idx & 15;
                const int grow = row0 + m * 16 + (rb >> 4) * 64 + (rb & 15);
                u16x8 pk;
#pragma unroll
                for (int e = 0; e < 8; ++e) pk[e] = f2bf(Epi2[rb][c8 * 8 + e]);
                *reinterpret_cast<u16x8*>(&vproj[(size_t)grow * 128 + c8 * 8]) = pk;
            }
            __syncthreads();
        }
    } else {
        // ================= logits path (batch = lid&7) ====================
        auto Asub = reinterpret_cast<unsigned short(*)[64][8]>(SMEM);           // 4 KB
        auto Bsub = reinterpret_cast<unsigned short(*)[192][8]>(SMEM + 4096);   // 12 KB

        const int lid = bid - 224;               // 224 % 8 == 0 -> lid&7 == bid&7
        const int qrow0 = (lid & 7) * 2048 + (lid >> 3) * 64;
        const int wr = w >> 1, wc = w & 1;          // wave: 32 rows x 96 cols

        f32x4 acc[2][6];
#pragma unroll
        for (int m = 0; m < 2; ++m)
#pragma unroll
            for (int n = 0; n < 6; ++n) acc[m][n] = (f32x4){0.f, 0.f, 0.f, 0.f};

        const int ar = t >> 2, as = t & 3;          // A staging: row 0..63, slot 0..3

        for (int k0t = 0; k0t < 8; ++k0t) {
            const int k0 = k0t * 32;
            {   // stage A: 64 rows x 32 k, f32 -> bf16
                const float* src = &query[(size_t)(qrow0 + ar) * 256 + k0 + as * 8];
                const float4 f0 = *reinterpret_cast<const float4*>(src);
                const float4 f1 = *reinterpret_cast<const float4*>(src + 4);
                u16x8 pk;
                pk[0]=f2bf(f0.x); pk[1]=f2bf(f0.y); pk[2]=f2bf(f0.z); pk[3]=f2bf(f0.w);
                pk[4]=f2bf(f1.x); pk[5]=f2bf(f1.y); pk[6]=f2bf(f1.z); pk[7]=f2bf(f1.w);
                *reinterpret_cast<u16x8*>(&Asub[as][ar][0]) = pk;
            }
            {   // stage B from raw [Woff|Waw] (col<96 -> Woff, else Waw)
#pragma unroll
                for (int i = 0; i < 3; ++i) {
                    const int c = t + i * 256;      // 0..767
                    const int slot = c / 192, col = c % 192;
                    u16x8 pk;
#pragma unroll
                    for (int jj = 0; jj < 8; ++jj) {
                        const int kk = k0 + slot * 8 + jj;
                        const float v = (col < 96) ? Woff[kk * 96 + col]
                                                   : Waw[kk * 96 + (col - 96)];
                        pk[jj] = f2bf(v);
                    }
                    *reinterpret_cast<u16x8*>(&Bsub[slot][col][0]) = pk;
                }
            }
            __syncthreads();

            bf16x8 bfrag[6];
#pragma unroll
            for (int n = 0; n < 6; ++n)
                bfrag[n] = *reinterpret_cast<bf16x8*>(&Bsub[sl][wc * 96 + n * 16 + fr][0]);
#pragma unroll
            for (int m = 0; m < 2; ++m) {
                bf16x8 afrag = *reinterpret_cast<bf16x8*>(&Asub[sl][wr * 32 + m * 16 + fr][0]);
#pragma unroll
                for (int n = 0; n < 6; ++n)
                    acc[m][n] = __builtin_amdgcn_mfma_f32_16x16x32_bf16(afrag, bfrag[n], acc[m][n], 0, 0, 0);
            }
            __syncthreads();
        }

        // Epilogue in two 32-row halves through the union buffer.
        auto Epi = reinterpret_cast<float(*)[196]>(SMEM);    // [32][196], aliases staging
#pragma unroll
        for (int half = 0; half < 2; ++half) {
            if (half) __syncthreads();               // protect Epi reuse across halves
            if (wr == half) {
#pragma unroll
                for (int n = 0; n < 6; ++n) {
                    const int col = wc * 96 + n * 16 + fr;
                    const float bsn = (col < 96) ? boff[col] : baw[col - 96];
#pragma unroll
                    for (int m = 0; m < 2; ++m)
#pragma unroll
                        for (int jj = 0; jj < 4; ++jj)
                            Epi[m * 16 + sl * 4 + jj][col] = acc[m][n][jj] + bsn;
                }
            }
            __syncthreads();

            // softmax + sidx: 256 (q,h) pairs, 1 per thread
            {
                const int q = t >> 3, h = t & 7;
                const float ref = refp[qrow0 + half * 32 + q];
                float* lg = &Epi[q][96 + h * 12];
                float mx = -1e30f;
#pragma unroll
                for (int jj = 0; jj < 12; ++jj) mx = fmaxf(mx, lg[jj]);
                float e[12]; float s = 0.f;
#pragma unroll
                for (int jj = 0; jj < 12; ++jj) { e[jj] = expf(lg[jj] - mx); s += e[jj]; }
                const float inv = 1.f / s;
#pragma unroll
                for (int jj = 0; jj < 12; ++jj) lg[jj] = e[jj] * inv;
                float* off = &Epi[q][h * 12];
#pragma unroll
                for (int jj = 0; jj < 12; ++jj) {
                    const int l = jj >> 2;
                    const int T = 2048 >> l;
                    float pos = ref + off[jj] / (float)T;
                    pos = fminf(fmaxf(pos, 0.f), 1.f);
                    off[jj] = pos * (float)(T - 1);
                }
            }
            __syncthreads();

            // Coalesced writeout: 32 x 192 f32 = 1536 float4, 6 per thread.
#pragma unroll
            for (int i = 0; i < 6; ++i) {
                const int idx = t + i * 256;
                const int q = idx / 48, c4 = idx % 48;
                const float4 o = *reinterpret_cast<const float4*>(&Epi[q][c4 * 4]);
                *reinterpret_cast<float4*>(
                    &rows[(size_t)(qrow0 + half * 32 + q) * 192 + c4 * 4]) = o;
            }
        }
    }
}

// ---------------------------------------------------------------------------
// K3: gather + lerp + weighted sum, 4x vectorized.
// One wave per query (8 heads x 8 channel-quads), 4 queries per block.
// ushort4 (8B) gathers; grid 4096 with bid&7 = batch -> XCD L2 affinity.
// ---------------------------------------------------------------------------
__global__ __launch_bounds__(256) void sample_kernel(
    const float* __restrict__ rows,            // [16384,192]  sidx | aw
    const unsigned short* __restrict__ vproj,  // [28672,128]  bf16, level-major
    unsigned short* __restrict__ out_mid)      // [16384,256]  bf16
{
    const int bid = blockIdx.x;                // 0..4095
    const int b = bid & 7;
    const int q0 = (b << 11) + ((bid >> 3) << 2);   // 4 queries/block
    const int t = threadIdx.x;
    const int w = t >> 6, lane = t & 63;
    const int h = lane >> 3, c4 = lane & 7;    // channel = c4*4 .. +3

    __shared__ float srow[4][192];
    {
        const float* src = rows + (size_t)q0 * 192;
#pragma unroll
        for (int i = 0; i < 3; ++i) {
            const int idx = t + i * 256;       // 0..767, coalesced
            srow[idx / 192][idx % 192] = src[idx];
        }
    }
    __syncthreads();

    float acc0 = 0.f, acc1 = 0.f, acc2 = 0.f, acc3 = 0.f;
#pragma unroll
    for (int l = 0; l < 3; ++l) {
        const int T = 2048 >> l;
        const int loff = (l == 0) ? 0 : ((l == 1) ? 16384 : 24576);
#pragma unroll
        for (int p = 0; p < 4; ++p) {
            const int j = h * 12 + l * 4 + p;
            const float wgt  = srow[w][96 + j];
            const float sidx = srow[w][j];
            int ifl = (int)sidx;
            ifl = min(max(ifl, 0), T - 2);
            const float wce = sidx - (float)ifl;
            const size_t base = ((size_t)(loff + b * T + ifl)) * 128 + p * 32 + c4 * 4;
            const ushort4 vf = *reinterpret_cast<const ushort4*>(&vproj[base]);
            const ushort4 vc = *reinterpret_cast<const ushort4*>(&vproj[base + 128]);
            const float f0 = bf2f(vf.x), f1 = bf2f(vf.y), f2 = bf2f(vf.z), f3 = bf2f(vf.w);
            const float g0 = bf2f(vc.x), g1 = bf2f(vc.y), g2 = bf2f(vc.z), g3 = bf2f(vc.w);
            acc0 += wgt * (f0 + wce * (g0 - f0));
            acc1 += wgt * (f1 + wce * (g1 - f1));
            acc2 += wgt * (f2 + wce * (g2 - f2));
            acc3 += wgt * (f3 + wce * (g3 - f3));
        }
    }
    ushort4 o;
    o.x = f2bf(acc0); o.y = f2bf(acc1); o.z = f2bf(acc2); o.w = f2bf(acc3);
    *reinterpret_cast<ushort4*>(&out_mid[(size_t)(q0 + w) * 256 + h * 32 + c4 * 4]) = o;
}

// ---------------------------------------------------------------------------
// K4: output projection, XCD-batch-aligned, LDS phase-union (16.9 KB).
// B staged directly from raw Wo (f32, coalesced, L2-hot).
// 1D grid 256: b = bid&7, row-tile = (bid>>3)&15, col-tile = bid>>7.
// ---------------------------------------------------------------------------
__global__ __launch_bounds__(256) void outproj_kernel(
    const unsigned short* __restrict__ omid,   // [16384,256] bf16
    const float* __restrict__ Wo,              // [256][256] f32
    const float* __restrict__ bo,
    float* __restrict__ out)
{
    __shared__ __align__(16) char SMEM[16896];   // union: staging 16K | epi 16.9K
    auto Asub = reinterpret_cast<unsigned short(*)[128][8]>(SMEM);          // 8 KB
    auto Bsub = reinterpret_cast<unsigned short(*)[128][8]>(SMEM + 8192);   // 8 KB

    const int t = threadIdx.x;
    const int bid = blockIdx.x;
    const int b = bid & 7;
    const int row0 = b * 2048 + ((bid >> 3) & 15) * 128;
    const int col0 = (bid >> 7) * 128;

    const int ar = t >> 1, ah = t & 1;
    const int w = t >> 6, lane = t & 63;
    const int wr = w >> 1, wc = w & 1;
    const int fr = lane & 15, sl = lane >> 4;

    f32x4 acc[4][4];
#pragma unroll
    for (int m = 0; m < 4; ++m)
#pragma unroll
        for (int n = 0; n < 4; ++n) acc[m][n] = (f32x4){0.f, 0.f, 0.f, 0.f};

    for (int k0t = 0; k0t < 8; ++k0t) {
        const int k0 = k0t * 32;
#pragma unroll
        for (int q = 0; q < 2; ++q) {           // stage A: 16B copies (bf16 src)
            const int slot = ah * 2 + q;
            *reinterpret_cast<u16x8*>(&Asub[slot][ar][0]) =
                *reinterpret_cast<const u16x8*>(&omid[(size_t)(row0 + ar) * 256 + k0 + slot * 8]);
        }
        {                                        // stage B from raw Wo
#pragma unroll
            for (int i = 0; i < 2; ++i) {
                const int ch = t + i * 256;      // 0..511
                const int slot = ch >> 7, col = col0 + (ch & 127);
                u16x8 pk;
#pragma unroll
                for (int jj = 0; jj < 8; ++jj)
                    pk[jj] = f2bf(Wo[(size_t)(k0 + slot * 8 + jj) * 256 + col]);
                *reinterpret_cast<u16x8*>(&Bsub[slot][ch & 127][0]) = pk;
            }
        }
        __syncthreads();

        bf16x8 bfrag[4];
#pragma unroll
        for (int n = 0; n < 4; ++n)
            bfrag[n] = *reinterpret_cast<bf16x8*>(&Bsub[sl][wc * 64 + n * 16 + fr][0]);
#pragma unroll
        for (int m = 0; m < 4; ++m) {
            bf16x8 afrag = *reinterpret_cast<bf16x8*>(&Asub[sl][wr * 64 + m * 16 + fr][0]);
#pragma unroll
            for (int n = 0; n < 4; ++n)
                acc[m][n] = __builtin_amdgcn_mfma_f32_16x16x32_bf16(afrag, bfrag[n], acc[m][n], 0, 0, 0);
        }
        __syncthreads();
    }

    float bs[4];
#pragma unroll
    for (int n = 0; n < 4; ++n) bs[n] = bo[col0 + wc * 64 + n * 16 + fr];

    auto Epi2 = reinterpret_cast<float(*)[132]>(SMEM);   // [32][132], aliases staging
#pragma unroll
    for (int m = 0; m < 4; ++m) {
#pragma unroll
        for (int n = 0; n < 4; ++n)
#pragma unroll
            for (int j = 0; j < 4; ++j)
                Epi2[wr * 16 + sl * 4 + j][wc * 64 + n * 16 + fr] = acc[m][n][j] + bs[n];
        __syncthreads();
#pragma unroll
        for (int i = 0; i < 4; ++i) {            // 1024 float4 chunks, 4/thread
            const int idx = t + i * 256;
            const int rb = idx >> 5, c4 = idx & 31;
            const int grow = row0 + m * 16 + (rb >> 4) * 64 + (rb & 15);
            const float4 o = *reinterpret_cast<const float4*>(&Epi2[rb][c4 * 4]);
            *reinterpret_cast<float4*>(&out[(size_t)grow * 256 + col0 + c4 * 4]) = o;
        }
        __syncthreads();
    }
}

extern "C" void kernel_launch(void* const* d_in, const int* in_sizes, int n_in,
                              void* d_out, int out_size, void* d_ws, size_t ws_size,
                              hipStream_t stream) {
    (void)in_sizes; (void)n_in; (void)out_size; (void)ws_size;
    const float* query = (const float*)d_in[0];
    const float* refp  = (const float*)d_in[1];
    const float* v0    = (const float*)d_in[2];
    const float* v1    = (const float*)d_in[3];
    const float* v2    = (const float*)d_in[4];
    const float* Woff  = (const float*)d_in[5];
    const float* boff  = (const float*)d_in[6];
    const float* Waw   = (const float*)d_in[7];
    const float* baw   = (const float*)d_in[8];
    const float* Wv    = (const float*)d_in[9];
    const float* bv    = (const float*)d_in[10];
    const float* Wo    = (const float*)d_in[11];
    const float* bo    = (const float*)d_in[12];
    float* out = (float*)d_out;

    char* ws = (char*)d_ws;
    unsigned short* vproj = (unsigned short*)(ws);             // 7,340,032 B
    float*          rows  = (float*)(ws + 7340032);            // 12,582,912 B
    unsigned short* omid  = (unsigned short*)(ws + 19922944);  // 8,388,608 B

    // K12: merged vproj + logits/softmax/sidx (weights staged raw, no K0)
    fused_k12_kernel<<<480, 256, 0, stream>>>(v0, v1, v2, Wv, bv, vproj,
                                              query, Woff, Waw, boff, baw,
                                              refp, rows);

    // K3: gather + lerp + weighted sum (vectorized, XCD-aligned)
    sample_kernel<<<4096, 256, 0, stream>>>(rows, vproj, omid);

    // K4: output projection (B staged raw)
    outproj_kernel<<<256, 256, 0, stream>>>(omid, Wo, bo, out);
}

// Round 13
// 47.594 us; speedup vs baseline: 1.7999x; 1.0473x over previous
//
#include <hip/hip_runtime.h>
#include <stdint.h>

// B=8, Q=2048, D=256, H=8, L=3, P=4, HD=32
// vproj rows: level-major, T={2048,1024,512}, LOFF={0,16384,24576}, total 28672

typedef __attribute__((ext_vector_type(8))) short bf16x8;
typedef __attribute__((ext_vector_type(8))) unsigned short u16x8;
typedef __attribute__((ext_vector_type(4))) float f32x4;

__device__ __forceinline__ unsigned short f2bf(float f) {
    union { float f; uint32_t u; } v; v.f = f;
    return (unsigned short)((v.u + 0x7FFFu + ((v.u >> 16) & 1u)) >> 16);  // RNE
}
__device__ __forceinline__ float bf2f(unsigned short u) {
    union { uint32_t u; float f; } v; v.u = ((uint32_t)u) << 16;
    return v.f;
}

// ---------------------------------------------------------------------------
// K12: merged GEMMs, small tiles for grid-level latency hiding (960 blocks
// ~3.75/CU — round 12 insight: grid size, not LDS, capped occupancy).
//  blocks 0..447  : vproj tile 64x128 (batch = bid&7, 56 tiles/batch).
//  blocks 448..959: logits tile 32x192 (batch = lid&7) + softmax + sidx.
// No min-waves launch_bounds (round 9: (256,6) spilled accumulators).
// ---------------------------------------------------------------------------
__global__ __launch_bounds__(256) void fused_k12_kernel(
    const float* __restrict__ v0, const float* __restrict__ v1,
    const float* __restrict__ v2,
    const float* __restrict__ Wv, const float* __restrict__ bv,
    unsigned short* __restrict__ vproj,
    const float* __restrict__ query,
    const float* __restrict__ Woff, const float* __restrict__ Waw,
    const float* __restrict__ boff, const float* __restrict__ baw,
    const float* __restrict__ refp, float* __restrict__ rows)
{
    __shared__ __align__(16) char SMEM[25344];   // union: staging | epilogue
    const int t = threadIdx.x;
    const int bid = blockIdx.x;
    const int w = t >> 6, lane = t & 63;
    const int fr = lane & 15, sl = lane >> 4;

    if (bid < 448) {
        // ============ vproj path: 64x128 tile (batch = bid&7) =============
        auto Asub = reinterpret_cast<unsigned short(*)[64][8]>(SMEM);           // 4 KB
        auto Bsub = reinterpret_cast<unsigned short(*)[128][8]>(SMEM + 4096);   // 8 KB

        const int b = bid & 7;
        const int j = bid >> 3;                  // 0..55
        int l, tile;
        if (j < 32)      { l = 0; tile = j; }
        else if (j < 48) { l = 1; tile = j - 32; }
        else             { l = 2; tile = j - 48; }
        const int T = 2048 >> l;
        const int loff = (l == 0) ? 0 : ((l == 1) ? 16384 : 24576);
        const int row0 = loff + b * T + tile * 64;
        const int arow = b * T + tile * 64;
        const float* Ap = (l == 0) ? v0 : ((l == 1) ? v1 : v2);

        const int ar = t >> 2, as = t & 3;       // A staging: row 0..63, slot
        const int wr = w >> 1, wc = w & 1;       // wave: 32 rows x 64 cols

        f32x4 acc[2][4];
#pragma unroll
        for (int m = 0; m < 2; ++m)
#pragma unroll
            for (int n = 0; n < 4; ++n) acc[m][n] = (f32x4){0.f, 0.f, 0.f, 0.f};

        for (int k0t = 0; k0t < 8; ++k0t) {
            const int k0 = k0t * 32;
            {   // stage A: 64 rows x 32 k (f32 -> bf16), 1 chunk/thread
                const float* src = &Ap[(size_t)(arow + ar) * 256 + k0 + as * 8];
                const float4 f0 = *reinterpret_cast<const float4*>(src);
                const float4 f1 = *reinterpret_cast<const float4*>(src + 4);
                u16x8 pk;
                pk[0]=f2bf(f0.x); pk[1]=f2bf(f0.y); pk[2]=f2bf(f0.z); pk[3]=f2bf(f0.w);
                pk[4]=f2bf(f1.x); pk[5]=f2bf(f1.y); pk[6]=f2bf(f1.z); pk[7]=f2bf(f1.w);
                *reinterpret_cast<u16x8*>(&Asub[as][ar][0]) = pk;
            }
            {   // stage B from raw Wv (cols 0..127), 2 chunks/thread
#pragma unroll
                for (int i = 0; i < 2; ++i) {
                    const int ch = t + i * 256;
                    const int slot = ch >> 7, col = ch & 127;
                    u16x8 pk;
#pragma unroll
                    for (int jj = 0; jj < 8; ++jj)
                        pk[jj] = f2bf(Wv[(size_t)(k0 + slot * 8 + jj) * 256 + col]);
                    *reinterpret_cast<u16x8*>(&Bsub[slot][col][0]) = pk;
                }
            }
            __syncthreads();

            bf16x8 bfrag[4];
#pragma unroll
            for (int n = 0; n < 4; ++n)
                bfrag[n] = *reinterpret_cast<bf16x8*>(&Bsub[sl][wc * 64 + n * 16 + fr][0]);
#pragma unroll
            for (int m = 0; m < 2; ++m) {
                bf16x8 afrag = *reinterpret_cast<bf16x8*>(&Asub[sl][wr * 32 + m * 16 + fr][0]);
#pragma unroll
                for (int n = 0; n < 4; ++n)
                    acc[m][n] = __builtin_amdgcn_mfma_f32_16x16x32_bf16(afrag, bfrag[n], acc[m][n], 0, 0, 0);
            }
            __syncthreads();
        }

        float bs[4];
#pragma unroll
        for (int n = 0; n < 4; ++n) bs[n] = bv[wc * 64 + n * 16 + fr];

        auto Epi2 = reinterpret_cast<float(*)[132]>(SMEM);   // [32][132], aliases staging
#pragma unroll
        for (int m = 0; m < 2; ++m) {
#pragma unroll
            for (int n = 0; n < 4; ++n)
#pragma unroll
                for (int jj = 0; jj < 4; ++jj)
                    Epi2[wr * 16 + sl * 4 + jj][wc * 64 + n * 16 + fr] = acc[m][n][jj] + bs[n];
            __syncthreads();
#pragma unroll
            for (int i = 0; i < 2; ++i) {            // 32x128 bf16 = 512 chunks
                const int idx = t + i * 256;
                const int rb = idx >> 4, c8 = idx & 15;
                const int grow = row0 + m * 16 + (rb >> 4) * 32 + (rb & 15);
                u16x8 pk;
#pragma unroll
                for (int e = 0; e < 8; ++e) pk[e] = f2bf(Epi2[rb][c8 * 8 + e]);
                *reinterpret_cast<u16x8*>(&vproj[(size_t)grow * 128 + c8 * 8]) = pk;
            }
            __syncthreads();
        }
    } else {
        // ============ logits path: 32x192 tile (batch = lid&7) ============
        auto Asub = reinterpret_cast<unsigned short(*)[32][8]>(SMEM);           // 2 KB
        auto Bsub = reinterpret_cast<unsigned short(*)[192][8]>(SMEM + 2048);   // 12 KB

        const int lid = bid - 448;               // 448 % 8 == 0
        const int qrow0 = (lid & 7) * 2048 + (lid >> 3) * 32;
        const int wr = w >> 1, wc = w & 1;       // wave: 16 rows x 96 cols

        f32x4 acc[6];
#pragma unroll
        for (int n = 0; n < 6; ++n) acc[n] = (f32x4){0.f, 0.f, 0.f, 0.f};

        const int ar = t >> 2, as = t & 3;       // A staging (t<128): row, slot

        for (int k0t = 0; k0t < 8; ++k0t) {
            const int k0 = k0t * 32;
            if (t < 128) {   // stage A: 32 rows x 32 k
                const float* src = &query[(size_t)(qrow0 + ar) * 256 + k0 + as * 8];
                const float4 f0 = *reinterpret_cast<const float4*>(src);
                const float4 f1 = *reinterpret_cast<const float4*>(src + 4);
                u16x8 pk;
                pk[0]=f2bf(f0.x); pk[1]=f2bf(f0.y); pk[2]=f2bf(f0.z); pk[3]=f2bf(f0.w);
                pk[4]=f2bf(f1.x); pk[5]=f2bf(f1.y); pk[6]=f2bf(f1.z); pk[7]=f2bf(f1.w);
                *reinterpret_cast<u16x8*>(&Asub[as][ar][0]) = pk;
            }
            {   // stage B from raw [Woff|Waw], 3 chunks/thread
#pragma unroll
                for (int i = 0; i < 3; ++i) {
                    const int c = t + i * 256;      // 0..767
                    const int slot = c / 192, col = c % 192;
                    u16x8 pk;
#pragma unroll
                    for (int jj = 0; jj < 8; ++jj) {
                        const int kk = k0 + slot * 8 + jj;
                        const float v = (col < 96) ? Woff[kk * 96 + col]
                                                   : Waw[kk * 96 + (col - 96)];
                        pk[jj] = f2bf(v);
                    }
                    *reinterpret_cast<u16x8*>(&Bsub[slot][col][0]) = pk;
                }
            }
            __syncthreads();

            bf16x8 afrag = *reinterpret_cast<bf16x8*>(&Asub[sl][wr * 16 + fr][0]);
#pragma unroll
            for (int n = 0; n < 6; ++n) {
                bf16x8 bfrag = *reinterpret_cast<bf16x8*>(&Bsub[sl][wc * 96 + n * 16 + fr][0]);
                acc[n] = __builtin_amdgcn_mfma_f32_16x16x32_bf16(afrag, bfrag, acc[n], 0, 0, 0);
            }
            __syncthreads();
        }

        // Epilogue: all 32 rows at once through the union buffer.
        auto Epi = reinterpret_cast<float(*)[196]>(SMEM);    // [32][196]
#pragma unroll
        for (int n = 0; n < 6; ++n) {
            const int col = wc * 96 + n * 16 + fr;
            const float bsn = (col < 96) ? boff[col] : baw[col - 96];
#pragma unroll
            for (int jj = 0; jj < 4; ++jj)
                Epi[wr * 16 + sl * 4 + jj][col] = acc[n][jj] + bsn;
        }
        __syncthreads();

        // softmax + sidx: 32 q x 8 h = 256 pairs, 1 per thread
        {
            const int q = t >> 3, h = t & 7;
            const float ref = refp[qrow0 + q];
            float* lg = &Epi[q][96 + h * 12];
            float mx = -1e30f;
#pragma unroll
            for (int jj = 0; jj < 12; ++jj) mx = fmaxf(mx, lg[jj]);
            float e[12]; float s = 0.f;
#pragma unroll
            for (int jj = 0; jj < 12; ++jj) { e[jj] = expf(lg[jj] - mx); s += e[jj]; }
            const float inv = 1.f / s;
#pragma unroll
            for (int jj = 0; jj < 12; ++jj) lg[jj] = e[jj] * inv;
            float* off = &Epi[q][h * 12];
#pragma unroll
            for (int jj = 0; jj < 12; ++jj) {
                const int l = jj >> 2;
                const int T = 2048 >> l;
                float pos = ref + off[jj] / (float)T;
                pos = fminf(fmaxf(pos, 0.f), 1.f);
                off[jj] = pos * (float)(T - 1);
            }
        }
        __syncthreads();

        // Coalesced writeout: 32 x 192 f32 = 1536 float4, 6 per thread.
#pragma unroll
        for (int i = 0; i < 6; ++i) {
            const int idx = t + i * 256;
            const int q = idx / 48, c4 = idx % 48;
            const float4 o = *reinterpret_cast<const float4*>(&Epi[q][c4 * 4]);
            *reinterpret_cast<float4*>(&rows[(size_t)(qrow0 + q) * 192 + c4 * 4]) = o;
        }
    }
}

// ---------------------------------------------------------------------------
// K3: gather + lerp + weighted sum, 4x vectorized.
// One wave per query (8 heads x 8 channel-quads), 4 queries per block.
// ushort4 (8B) gathers; grid 4096 with bid&7 = batch -> XCD L2 affinity.
// ---------------------------------------------------------------------------
__global__ __launch_bounds__(256) void sample_kernel(
    const float* __restrict__ rows,            // [16384,192]  sidx | aw
    const unsigned short* __restrict__ vproj,  // [28672,128]  bf16, level-major
    unsigned short* __restrict__ out_mid)      // [16384,256]  bf16
{
    const int bid = blockIdx.x;                // 0..4095
    const int b = bid & 7;
    const int q0 = (b << 11) + ((bid >> 3) << 2);   // 4 queries/block
    const int t = threadIdx.x;
    const int w = t >> 6, lane = t & 63;
    const int h = lane >> 3, c4 = lane & 7;    // channel = c4*4 .. +3

    __shared__ float srow[4][192];
    {
        const float* src = rows + (size_t)q0 * 192;
#pragma unroll
        for (int i = 0; i < 3; ++i) {
            const int idx = t + i * 256;       // 0..767, coalesced
            srow[idx / 192][idx % 192] = src[idx];
        }
    }
    __syncthreads();

    float acc0 = 0.f, acc1 = 0.f, acc2 = 0.f, acc3 = 0.f;
#pragma unroll
    for (int l = 0; l < 3; ++l) {
        const int T = 2048 >> l;
        const int loff = (l == 0) ? 0 : ((l == 1) ? 16384 : 24576);
#pragma unroll
        for (int p = 0; p < 4; ++p) {
            const int j = h * 12 + l * 4 + p;
            const float wgt  = srow[w][96 + j];
            const float sidx = srow[w][j];
            int ifl = (int)sidx;
            ifl = min(max(ifl, 0), T - 2);
            const float wce = sidx - (float)ifl;
            const size_t base = ((size_t)(loff + b * T + ifl)) * 128 + p * 32 + c4 * 4;
            const ushort4 vf = *reinterpret_cast<const ushort4*>(&vproj[base]);
            const ushort4 vc = *reinterpret_cast<const ushort4*>(&vproj[base + 128]);
            const float f0 = bf2f(vf.x), f1 = bf2f(vf.y), f2 = bf2f(vf.z), f3 = bf2f(vf.w);
            const float g0 = bf2f(vc.x), g1 = bf2f(vc.y), g2 = bf2f(vc.z), g3 = bf2f(vc.w);
            acc0 += wgt * (f0 + wce * (g0 - f0));
            acc1 += wgt * (f1 + wce * (g1 - f1));
            acc2 += wgt * (f2 + wce * (g2 - f2));
            acc3 += wgt * (f3 + wce * (g3 - f3));
        }
    }
    ushort4 o;
    o.x = f2bf(acc0); o.y = f2bf(acc1); o.z = f2bf(acc2); o.w = f2bf(acc3);
    *reinterpret_cast<ushort4*>(&out_mid[(size_t)(q0 + w) * 256 + h * 32 + c4 * 4]) = o;
}

// ---------------------------------------------------------------------------
// K4: output projection, 64x128 tiles -> 512 blocks (2/CU) for latency hiding.
// b = bid&7, row-tile = (bid>>3)&31, col-tile = bid>>8.
// ---------------------------------------------------------------------------
__global__ __launch_bounds__(256) void outproj_kernel(
    const unsigned short* __restrict__ omid,   // [16384,256] bf16
    const float* __restrict__ Wo,              // [256][256] f32
    const float* __restrict__ bo,
    float* __restrict__ out)
{
    __shared__ __align__(16) char SMEM[16896];   // union: staging 12K | epi 16.9K
    auto Asub = reinterpret_cast<unsigned short(*)[64][8]>(SMEM);           // 4 KB
    auto Bsub = reinterpret_cast<unsigned short(*)[128][8]>(SMEM + 4096);   // 8 KB

    const int t = threadIdx.x;
    const int bid = blockIdx.x;
    const int b = bid & 7;
    const int row0 = b * 2048 + ((bid >> 3) & 31) * 64;
    const int col0 = (bid >> 8) * 128;

    const int ar = t >> 2, as = t & 3;           // A staging: row 0..63, slot
    const int w = t >> 6, lane = t & 63;
    const int wr = w >> 1, wc = w & 1;           // wave: 32 rows x 64 cols
    const int fr = lane & 15, sl = lane >> 4;

    f32x4 acc[2][4];
#pragma unroll
    for (int m = 0; m < 2; ++m)
#pragma unroll
        for (int n = 0; n < 4; ++n) acc[m][n] = (f32x4){0.f, 0.f, 0.f, 0.f};

    for (int k0t = 0; k0t < 8; ++k0t) {
        const int k0 = k0t * 32;
        {   // stage A: 16B copies (bf16 src), 1 chunk/thread
            *reinterpret_cast<u16x8*>(&Asub[as][ar][0]) =
                *reinterpret_cast<const u16x8*>(&omid[(size_t)(row0 + ar) * 256 + k0 + as * 8]);
        }
        {   // stage B from raw Wo, 2 chunks/thread
#pragma unroll
            for (int i = 0; i < 2; ++i) {
                const int ch = t + i * 256;
                const int slot = ch >> 7, col = col0 + (ch & 127);
                u16x8 pk;
#pragma unroll
                for (int jj = 0; jj < 8; ++jj)
                    pk[jj] = f2bf(Wo[(size_t)(k0 + slot * 8 + jj) * 256 + col]);
                *reinterpret_cast<u16x8*>(&Bsub[slot][ch & 127][0]) = pk;
            }
        }
        __syncthreads();

        bf16x8 bfrag[4];
#pragma unroll
        for (int n = 0; n < 4; ++n)
            bfrag[n] = *reinterpret_cast<bf16x8*>(&Bsub[sl][wc * 64 + n * 16 + fr][0]);
#pragma unroll
        for (int m = 0; m < 2; ++m) {
            bf16x8 afrag = *reinterpret_cast<bf16x8*>(&Asub[sl][wr * 32 + m * 16 + fr][0]);
#pragma unroll
            for (int n = 0; n < 4; ++n)
                acc[m][n] = __builtin_amdgcn_mfma_f32_16x16x32_bf16(afrag, bfrag[n], acc[m][n], 0, 0, 0);
        }
        __syncthreads();
    }

    float bs[4];
#pragma unroll
    for (int n = 0; n < 4; ++n) bs[n] = bo[col0 + wc * 64 + n * 16 + fr];

    auto Epi2 = reinterpret_cast<float(*)[132]>(SMEM);   // [32][132], aliases staging
#pragma unroll
    for (int m = 0; m < 2; ++m) {
#pragma unroll
        for (int n = 0; n < 4; ++n)
#pragma unroll
            for (int j = 0; j < 4; ++j)
                Epi2[wr * 16 + sl * 4 + j][wc * 64 + n * 16 + fr] = acc[m][n][j] + bs[n];
        __syncthreads();
#pragma unroll
        for (int i = 0; i < 4; ++i) {            // 32x128 f32 = 1024 float4
            const int idx = t + i * 256;
            const int rb = idx >> 5, c4 = idx & 31;
            const int grow = row0 + m * 16 + (rb >> 4) * 32 + (rb & 15);
            const float4 o = *reinterpret_cast<const float4*>(&Epi2[rb][c4 * 4]);
            *reinterpret_cast<float4*>(&out[(size_t)grow * 256 + col0 + c4 * 4]) = o;
        }
        __syncthreads();
    }
}

extern "C" void kernel_launch(void* const* d_in, const int* in_sizes, int n_in,
                              void* d_out, int out_size, void* d_ws, size_t ws_size,
                              hipStream_t stream) {
    (void)in_sizes; (void)n_in; (void)out_size; (void)ws_size;
    const float* query = (const float*)d_in[0];
    const float* refp  = (const float*)d_in[1];
    const float* v0    = (const float*)d_in[2];
    const float* v1    = (const float*)d_in[3];
    const float* v2    = (const float*)d_in[4];
    const float* Woff  = (const float*)d_in[5];
    const float* boff  = (const float*)d_in[6];
    const float* Waw   = (const float*)d_in[7];
    const float* baw   = (const float*)d_in[8];
    const float* Wv    = (const float*)d_in[9];
    const float* bv    = (const float*)d_in[10];
    const float* Wo    = (const float*)d_in[11];
    const float* bo    = (const float*)d_in[12];
    float* out = (float*)d_out;

    char* ws = (char*)d_ws;
    unsigned short* vproj = (unsigned short*)(ws);             // 7,340,032 B
    float*          rows  = (float*)(ws + 7340032);            // 12,582,912 B
    unsigned short* omid  = (unsigned short*)(ws + 19922944);  // 8,388,608 B

    // K12: merged vproj (448 blocks, 64x128) + logits (512 blocks, 32x192)
    fused_k12_kernel<<<960, 256, 0, stream>>>(v0, v1, v2, Wv, bv, vproj,
                                              query, Woff, Waw, boff, baw,
                                              refp, rows);

    // K3: gather + lerp + weighted sum (vectorized, XCD-aligned)
    sample_kernel<<<4096, 256, 0, stream>>>(rows, vproj, omid);

    // K4: output projection (64x128 tiles, 512 blocks)
    outproj_kernel<<<512, 256, 0, stream>>>(omid, Wo, bo, out);
}